// Round 5
// baseline (1264.089 us; speedup 1.0000x reference)
//
#include <hip/hip_runtime.h>
#include <math.h>

#define B_   64
#define T_   2048
#define HID_ 128
#define G3_  384   // 3*HID
#define IN_  128
#define E_   64

#define TS_      128            // t-tile of one gi job
#define NCHUNK_  (T_ / TS_)     // 16
#define NPROD_   192            // producer blocks in the mega dispatch
#define POLL_TGT 512            // 64 jobs/chunk * 8 wave-releases/job

typedef _Float16 f16x8 __attribute__((ext_vector_type(8)));
typedef float    f32x4 __attribute__((ext_vector_type(4)));

#define L2E  1.4426950408889634f   // log2(e)
#define L2E2 2.8853900817779268f   // 2*log2(e)

#if __has_builtin(__builtin_amdgcn_exp2f)
#define EXP2(x) __builtin_amdgcn_exp2f(x)
#else
#define EXP2(x) __expf((x) * 0.6931471805599453f)
#endif

__device__ __forceinline__ float rcp_(float x) { return __builtin_amdgcn_rcpf(x); }

// pack 8 f32 -> f16x8 via 4x cvt_pkrtz
__device__ __forceinline__ f16x8 pack8_(float4 a, float4 b) {
    uint4 u;
    u.x = __builtin_bit_cast(unsigned, __builtin_amdgcn_cvt_pkrtz(a.x, a.y));
    u.y = __builtin_bit_cast(unsigned, __builtin_amdgcn_cvt_pkrtz(a.z, a.w));
    u.z = __builtin_bit_cast(unsigned, __builtin_amdgcn_cvt_pkrtz(b.x, b.y));
    u.w = __builtin_bit_cast(unsigned, __builtin_amdgcn_cvt_pkrtz(b.z, b.w));
    return __builtin_bit_cast(f16x8, u);
}

// ---------------------------------------------------------------------------
// One gi job: 128 t-rows (tile tt) x one batch b, 8 waves / 512 threads,
// two column passes of 12 n-tiles (round-4-verified, ~64 VGPR).
// x rows = t0 + tt*128 + ...; gi rows = tt*128 + ... (tt is absolute in the
// mega path where t0 = 0 and gi is the full-T buffer; chunk-relative in the
// serial fallback).
// ---------------------------------------------------------------------------
__device__ __forceinline__ void gemm_body(
    int tt, int b, int t0,
    const float* __restrict__ x, const float* __restrict__ w_ih,
    const float* __restrict__ b_ih, const float* __restrict__ b_hh,
    float* gi)
{
    const int tid = threadIdx.x;
    const int w   = tid >> 6;      // 0..7
    const int l   = tid & 63;
    const int ln  = l & 15;
    const int kq  = l >> 4;
    const int tl_base = tt * TS_ + w * 16;

    const float* xb = x + ((size_t)b * T_ + (size_t)(t0 + tl_base)) * IN_;

    f16x8 afr[4];
    #pragma unroll
    for (int kc = 0; kc < 4; kc++) {
        const float* xr = xb + (size_t)ln * IN_ + kc * 32 + kq * 8;
        float4 p0 = *reinterpret_cast<const float4*>(xr);
        float4 p1 = *reinterpret_cast<const float4*>(xr + 4);
        afr[kc] = pack8_(p0, p1);
    }

    #pragma unroll
    for (int half = 0; half < 2; half++) {
        f32x4 acc[12];
        #pragma unroll
        for (int j = 0; j < 12; j++) acc[j] = (f32x4){0.f, 0.f, 0.f, 0.f};

        #pragma unroll
        for (int kc = 0; kc < 4; kc++) {
            #pragma unroll
            for (int j = 0; j < 12; j++) {
                const int nt = half * 12 + j;
                const float* wr = w_ih + (size_t)(nt * 16 + ln) * IN_ + kc * 32 + kq * 8;
                float4 q0 = *reinterpret_cast<const float4*>(wr);
                float4 q1 = *reinterpret_cast<const float4*>(wr + 4);
                const f16x8 bfr = pack8_(q0, q1);
                acc[j] = __builtin_amdgcn_mfma_f32_16x16x32_f16(afr[kc], bfr, acc[j], 0, 0, 0);
            }
        }

        #pragma unroll
        for (int j = 0; j < 12; j++) {
            const int col = half * 192 + j * 16 + ln;
            const float bias = b_ih[col] + (col < 256 ? b_hh[col] : 0.f);
            #pragma unroll
            for (int r = 0; r < 4; r++) {
                const size_t trow = (size_t)(tl_base + kq * 4 + r);
                gi[trow * (B_ * G3_) + (size_t)b * G3_ + col] = acc[j][r] + bias;
            }
        }
    }
}

// ---------------------------------------------------------------------------
// GRU recurrence step. Split accumulators (aA: kc0,kc2 / aB: kc1,kc3) halve
// the MFMA dependency depth at the step tail; gate input = aA[0]+aB[0].
// Gates exp2-direct on pre-scaled w_hh fragments. One barrier per step.
// ---------------------------------------------------------------------------
#define REC_STEP(CUR, LD, TLOAD, PB)                                           \
  {                                                                            \
    const char* hb_ = (const char*)(&h2_sh[PB][0]) + kq * 16;                  \
    f16x8 af_[4];                                                              \
    af_[0] = __builtin_bit_cast(f16x8, *(const uint4*)(hb_));                  \
    af_[1] = __builtin_bit_cast(f16x8, *(const uint4*)(hb_ + 64));             \
    af_[2] = __builtin_bit_cast(f16x8, *(const uint4*)(hb_ + 128));            \
    af_[3] = __builtin_bit_cast(f16x8, *(const uint4*)(hb_ + 192));            \
    const float* gp_ = gib + (size_t)(TLOAD) * S;                              \
    LD[0] = gp_[cg]; LD[1] = gp_[cg + 128]; LD[2] = gp_[cg + 256];             \
    f32x4 aA_[3], aB_[3];                                                      \
    _Pragma("unroll")                                                          \
    for (int g = 0; g < 3; g++) {                                              \
      aA_[g] = (f32x4){0.f, 0.f, 0.f, 0.f};                                    \
      aB_[g] = (f32x4){0.f, 0.f, 0.f, 0.f};                                    \
    }                                                                          \
    _Pragma("unroll")                                                          \
    for (int g = 0; g < 3; g++)                                                \
      aA_[g] = __builtin_amdgcn_mfma_f32_16x16x32_f16(af_[0], wf[g][0], aA_[g], 0, 0, 0); \
    _Pragma("unroll")                                                          \
    for (int g = 0; g < 3; g++)                                                \
      aB_[g] = __builtin_amdgcn_mfma_f32_16x16x32_f16(af_[1], wf[g][1], aB_[g], 0, 0, 0); \
    _Pragma("unroll")                                                          \
    for (int g = 0; g < 3; g++)                                                \
      aA_[g] = __builtin_amdgcn_mfma_f32_16x16x32_f16(af_[2], wf[g][2], aA_[g], 0, 0, 0); \
    _Pragma("unroll")                                                          \
    for (int g = 0; g < 3; g++)                                                \
      aB_[g] = __builtin_amdgcn_mfma_f32_16x16x32_f16(af_[3], wf[g][3], aB_[g], 0, 0, 0); \
    const float q_  = CUR[2] * L2E2;                                           \
    const float yr_ = fmaf(CUR[0], L2E, aA_[0][0] + aB_[0][0]);                \
    const float r_  = rcp_(1.f + EXP2(-yr_));                                  \
    const float yz_ = fmaf(CUR[1], L2E, aA_[1][0] + aB_[1][0]);                \
    const float z_  = rcp_(1.f + EXP2(-yz_));                                  \
    const float yn_ = fmaf(r_, aA_[2][0] + aB_[2][0] + bh, q_);                \
    const float u_  = rcp_(1.f + EXP2(yn_));                                   \
    const float n_  = fmaf(-2.f, u_, 1.f);                                     \
    hj = n_ + z_ * (hj - n_);                                                  \
    hs += hj;                                                                  \
    if (kq == 0) h2_sh[(PB) ^ 1][cg] = (_Float16)hj;                           \
    __syncthreads();                                                           \
  }

// ---------------------------------------------------------------------------
// GRU recurrence body (8 waves, 2/SIMD; round-1-verified structure). When
// ctr != nullptr, poll per-chunk completion flags (agent-scope acquire) for
// chunk c and c+1 before consuming chunk c (prefetch reaches t+5, i.e. at
// most 2 rows into c+1). Producers never wait on anyone -> no deadlock.
// ---------------------------------------------------------------------------
__device__ __forceinline__ void rec_body(
    int b,
    const float* gi, const float* __restrict__ w_hh,
    const float* __restrict__ b_hh,
    const float* __restrict__ w_proj, const float* __restrict__ b_proj,
    float* __restrict__ out, float* __restrict__ state,
    int t0, int t1, const int* ctr)
{
    const int tid  = threadIdx.x;
    const int w    = tid >> 6;     // wave 0..7
    const int lane = tid & 63;
    const int ln   = lane & 15;
    const int kq   = lane >> 4;
    const int wh   = w & 3;
    const int f    = w >> 2;
    const int cg   = 16 * wh + ln + 64 * f;
    const int nT   = t1 - t0;      // multiple of 128

    __shared__ _Float16 h2_sh[2][HID_];
    __shared__ float pooled[HID_];

    // B-frags pre-scaled: r,z by log2(e); n by 2*log2(e) (exp2-direct gates)
    f16x8 wf[3][4];
    #pragma unroll
    for (int g = 0; g < 3; g++) {
        const float s = (g == 2) ? L2E2 : L2E;
        const float* wr = w_hh + (size_t)(128 * g + cg) * HID_;
        #pragma unroll
        for (int kc = 0; kc < 4; kc++) {
            const float* p = wr + kc * 32 + kq * 8;
            float4 q0 = *reinterpret_cast<const float4*>(p);
            float4 q1 = *reinterpret_cast<const float4*>(p + 4);
            q0.x *= s; q0.y *= s; q0.z *= s; q0.w *= s;
            q1.x *= s; q1.y *= s; q1.z *= s; q1.w *= s;
            wf[g][kc] = pack8_(q0, q1);
        }
    }
    const float bh = L2E2 * b_hh[256 + cg];

    float hj, hs;
    if (t0 == 0) { hj = hs = 0.f; }
    else {
        hj = state[b * HID_ + cg];
        hs = state[B_ * HID_ + b * HID_ + cg];
    }
    if (kq == 0) h2_sh[0][cg] = (_Float16)hj;
    __syncthreads();

    const float* gib = gi + (size_t)b * G3_;
    const size_t S = (size_t)B_ * G3_;

    float g0[3], g1[3], g2[3], g3[3];
    int pb = 0;
    const int nTm1 = nT - 1;
    const int nC = nT >> 7;        // chunks of 128 steps

    for (int c = 0; c < nC; c++) {
        if (ctr) {
            const int cw = (c + 1 < NCHUNK_) ? c + 1 : NCHUNK_ - 1;
            while (__hip_atomic_load(&ctr[c], __ATOMIC_ACQUIRE,
                                     __HIP_MEMORY_SCOPE_AGENT) < POLL_TGT)
                __builtin_amdgcn_s_sleep(8);
            while (__hip_atomic_load(&ctr[cw], __ATOMIC_ACQUIRE,
                                     __HIP_MEMORY_SCOPE_AGENT) < POLL_TGT)
                __builtin_amdgcn_s_sleep(8);
        }
        if (c == 0) {   // prime ring buffers AFTER chunk-0 flag
            const float* p0 = gib;
            const float* p1 = gib + S;
            g0[0] = p0[cg]; g0[1] = p0[cg + 128]; g0[2] = p0[cg + 256];
            g1[0] = p1[cg]; g1[1] = p1[cg + 128]; g1[2] = p1[cg + 256];
        }
        const int tb = c << 7;
        for (int tg = 0; tg < TS_; tg += 4) {
            const int t = tb + tg;
            int t2 = t + 2 < nTm1 ? t + 2 : nTm1;
            int t3 = t + 3 < nTm1 ? t + 3 : nTm1;
            int t4 = t + 4 < nTm1 ? t + 4 : nTm1;
            int t5 = t + 5 < nTm1 ? t + 5 : nTm1;
            REC_STEP(g0, g2, t2, pb); pb ^= 1;
            REC_STEP(g1, g3, t3, pb); pb ^= 1;
            REC_STEP(g2, g0, t4, pb); pb ^= 1;
            REC_STEP(g3, g1, t5, pb); pb ^= 1;
        }
    }

    if (t1 < T_) {
        if (kq == 0) {
            state[b * HID_ + cg]             = hj;
            state[B_ * HID_ + b * HID_ + cg] = hs;
        }
    } else {
        if (kq == 0) pooled[cg] = hs * (1.f / (float)T_);
        __syncthreads();
        if (tid < E_) {
            const float4* wpj = reinterpret_cast<const float4*>(w_proj + (size_t)tid * HID_);
            const float4* pp  = reinterpret_cast<const float4*>(pooled);
            float a0 = 0.f, a1 = 0.f, a2 = 0.f, a3 = 0.f;
            #pragma unroll
            for (int k = 0; k < 32; k++) {
                float4 wv = wpj[k]; float4 pv = pp[k];
                a0 = fmaf(wv.x, pv.x, a0);
                a1 = fmaf(wv.y, pv.y, a1);
                a2 = fmaf(wv.z, pv.z, a2);
                a3 = fmaf(wv.w, pv.w, a3);
            }
            out[b * E_ + tid] = (a0 + a1) + (a2 + a3) + b_proj[tid];
        }
    }
}

// ---------------------------------------------------------------------------
// Mega dispatch: blocks [0,nRec) = rec consumers; blocks [nRec, nRec+nProd)
// = persistent gi producers looping chunk-major over nJobs (chunk = j>>6,
// batch = j&63). Each WAVE releases its own stores via an agent-scope
// release atomicAdd (8 adds/job -> POLL_TGT=512/chunk), so no cross-wave
// visibility subtlety. 80 KB dynamic LDS (launch cfg) forces 1 block/CU:
// rec blocks never share a CU with anything. Producers wait on nobody ->
// deadlock-free regardless of scheduling.
// ---------------------------------------------------------------------------
__global__ __launch_bounds__(512, 1)
void fused(const float* __restrict__ x, const float* __restrict__ w_ih,
           const float* __restrict__ b_ih, const float* __restrict__ w_hh,
           const float* __restrict__ b_hh,
           const float* __restrict__ w_proj, const float* __restrict__ b_proj,
           const float* gi_rec, float* gi_out,
           float* out, float* state, int* ctr,
           int trec0, int trec1, int nRec, int nProd, int nJobs, int tg0)
{
    extern __shared__ char lds_pad_[];   // reserved via launch config
    (void)lds_pad_;
    const int bid = (int)blockIdx.x;
    if (bid < nRec) {
        rec_body(bid, gi_rec, w_hh, b_hh, w_proj, b_proj, out, state,
                 trec0, trec1, ctr);
    } else {
        const int p = bid - nRec;
        for (int j = p; j < nJobs; j += nProd) {
            gemm_body(j >> 6, j & 63, tg0, x, w_ih, b_ih, b_hh, gi_out);
            if (ctr && (threadIdx.x & 63) == 0)
                __hip_atomic_fetch_add(&ctr[j >> 6], 1, __ATOMIC_RELEASE,
                                       __HIP_MEMORY_SCOPE_AGENT);
        }
    }
}

extern "C" void kernel_launch(void* const* d_in, const int* in_sizes, int n_in,
                              void* d_out, int out_size, void* d_ws, size_t ws_size,
                              hipStream_t stream)
{
    const float* x      = (const float*)d_in[0];
    const float* w_ih   = (const float*)d_in[1];
    const float* w_hh   = (const float*)d_in[2];
    const float* b_ih   = (const float*)d_in[3];
    const float* b_hh   = (const float*)d_in[4];
    const float* w_proj = (const float*)d_in[5];
    const float* b_proj = (const float*)d_in[6];
    float* out = (float*)d_out;

    const size_t state_bytes = (size_t)2 * B_ * HID_ * sizeof(float);
    const size_t per_t = (size_t)B_ * G3_ * sizeof(float);
    const size_t gi_bytes = (size_t)T_ * per_t;                 // 201 MB

    if (ws_size >= gi_bytes + 256 + state_bytes) {
        // --- single persistent producer-consumer dispatch ---
        float* gi    = (float*)d_ws;
        int*   ctr   = (int*)((char*)d_ws + gi_bytes);
        float* state = (float*)((char*)d_ws + gi_bytes + 256);
        hipMemsetAsync(ctr, 0, NCHUNK_ * sizeof(int), stream);
        fused<<<dim3(B_ + NPROD_), dim3(512), 80 * 1024, stream>>>(
            x, w_ih, b_ih, w_hh, b_hh, w_proj, b_proj,
            gi, gi, out, state, ctr,
            0, T_, B_, NPROD_, NCHUNK_ * B_, 0);
    } else {
        // --- serial fallback: per chunk, gemm dispatch then rec dispatch ---
        size_t avail = ws_size > state_bytes ? ws_size - state_bytes : 0;
        int cT = (int)(avail / per_t);
        if (cT > T_) cT = T_;
        cT &= ~(TS_ - 1);
        if (cT < TS_) cT = TS_;
        float* buf0  = (float*)d_ws;
        float* state = (float*)((char*)d_ws + (size_t)cT * per_t);
        for (int t0 = 0; t0 < T_; t0 += cT) {
            int t1 = t0 + cT; if (t1 > T_) t1 = T_;
            const int jobs = ((t1 - t0) / TS_) * B_;
            fused<<<dim3(jobs), dim3(512), 0, stream>>>(
                x, w_ih, b_ih, w_hh, b_hh, w_proj, b_proj,
                buf0, buf0, out, state, nullptr,
                0, 0, 0, jobs, jobs, t0);
            fused<<<dim3(B_), dim3(512), 0, stream>>>(
                x, w_ih, b_ih, w_hh, b_hh, w_proj, b_proj,
                buf0, buf0, out, state, nullptr,
                t0, t1, B_, 1, 0, 0);
        }
    }
}

// Round 8
// 836.188 us; speedup vs baseline: 1.5117x; 1.5117x over previous
//
#include <hip/hip_runtime.h>
#include <math.h>

#define B_   64
#define T_   2048
#define HID_ 128
#define G3_  384   // 3*HID
#define IN_  128
#define E_   64

#define TS_  128   // t-tile of gi GEMM block
#define CT_  512   // pipeline chunk: 5 dispatches total (was 9 at 256); L3 live
                   // set = 2x50MB gi + 17MB x << 256MB (avoids r5 eviction)

typedef _Float16 f16x8 __attribute__((ext_vector_type(8)));
typedef float    f32x4 __attribute__((ext_vector_type(4)));

#define L2E  1.4426950408889634f   // log2(e)
#define L2E2 2.8853900817779268f   // 2*log2(e)

#if __has_builtin(__builtin_amdgcn_exp2f)
#define EXP2(x) __builtin_amdgcn_exp2f(x)
#else
#define EXP2(x) __expf((x) * 0.6931471805599453f)
#endif

__device__ __forceinline__ float rcp_(float x) { return __builtin_amdgcn_rcpf(x); }

// pack 8 f32 -> f16x8 via 4x cvt_pkrtz
__device__ __forceinline__ f16x8 pack8_(float4 a, float4 b) {
    uint4 u;
    u.x = __builtin_bit_cast(unsigned, __builtin_amdgcn_cvt_pkrtz(a.x, a.y));
    u.y = __builtin_bit_cast(unsigned, __builtin_amdgcn_cvt_pkrtz(a.z, a.w));
    u.z = __builtin_bit_cast(unsigned, __builtin_amdgcn_cvt_pkrtz(b.x, b.y));
    u.w = __builtin_bit_cast(unsigned, __builtin_amdgcn_cvt_pkrtz(b.z, b.w));
    return __builtin_bit_cast(f16x8, u);
}

// ---------------------------------------------------------------------------
// gi GEMM body, 8 waves / 512 threads, TWO column passes of 12 tiles each
// (round-4-passing version, unchanged). Wave w owns one 16-row m-tile; MFMA
// layout session-verified (A row = ln, C/D row = kq*4+r, col = ln). w_ih is
// walked once per pass (196 KB, L2-resident, shared by all gemm blocks).
// ---------------------------------------------------------------------------
__device__ __forceinline__ void gemm_body(
    int g, int nTiles, int t0,
    const float* __restrict__ x, const float* __restrict__ w_ih,
    const float* __restrict__ b_ih, const float* __restrict__ b_hh,
    float* __restrict__ gi)
{
    const int tid = threadIdx.x;
    const int w   = tid >> 6;      // 0..7
    const int l   = tid & 63;
    const int ln  = l & 15;
    const int kq  = l >> 4;
    const int tt  = g % nTiles;
    const int b   = g / nTiles;
    const int tl_base = tt * TS_ + w * 16;

    const float* xb = x + ((size_t)b * T_ + (size_t)(t0 + tl_base)) * IN_;

    // A-frags once: 4 x f16x8 = 16 VGPR, live across both passes
    f16x8 afr[4];
    #pragma unroll
    for (int kc = 0; kc < 4; kc++) {
        const float* xr = xb + (size_t)ln * IN_ + kc * 32 + kq * 8;
        float4 p0 = *reinterpret_cast<const float4*>(xr);
        float4 p1 = *reinterpret_cast<const float4*>(xr + 4);
        afr[kc] = pack8_(p0, p1);
    }

    #pragma unroll
    for (int half = 0; half < 2; half++) {
        f32x4 acc[12];
        #pragma unroll
        for (int j = 0; j < 12; j++) acc[j] = (f32x4){0.f, 0.f, 0.f, 0.f};

        #pragma unroll
        for (int kc = 0; kc < 4; kc++) {
            #pragma unroll
            for (int j = 0; j < 12; j++) {
                const int nt = half * 12 + j;
                const float* wr = w_ih + (size_t)(nt * 16 + ln) * IN_ + kc * 32 + kq * 8;
                float4 q0 = *reinterpret_cast<const float4*>(wr);
                float4 q1 = *reinterpret_cast<const float4*>(wr + 4);
                const f16x8 bfr = pack8_(q0, q1);
                acc[j] = __builtin_amdgcn_mfma_f32_16x16x32_f16(afr[kc], bfr, acc[j], 0, 0, 0);
            }
        }

        #pragma unroll
        for (int j = 0; j < 12; j++) {
            const int col = half * 192 + j * 16 + ln;
            const float bias = b_ih[col] + (col < 256 ? b_hh[col] : 0.f);
            #pragma unroll
            for (int r = 0; r < 4; r++) {
                const size_t trow = (size_t)(tl_base + kq * 4 + r);   // chunk-relative
                gi[trow * (B_ * G3_) + (size_t)b * G3_ + col] = acc[j][r] + bias;
            }
        }
    }
}

// ---------------------------------------------------------------------------
// GRU recurrence step (round-4-passing version, byte-identical). 8 waves
// (2/SIMD); replicated-A broadcast ds_read of packed-f16 h; gates
// exp2-direct on pre-scaled w_hh; gi prefetch depth 2 (ring-4).
// ---------------------------------------------------------------------------
#define REC_STEP(CUR, LD, TLOAD, PB)                                           \
  {                                                                            \
    const char* hb_ = (const char*)(&h2_sh[PB][0]) + kq * 16;                  \
    f16x8 af_[4];                                                              \
    af_[0] = __builtin_bit_cast(f16x8, *(const uint4*)(hb_));                  \
    af_[1] = __builtin_bit_cast(f16x8, *(const uint4*)(hb_ + 64));             \
    af_[2] = __builtin_bit_cast(f16x8, *(const uint4*)(hb_ + 128));            \
    af_[3] = __builtin_bit_cast(f16x8, *(const uint4*)(hb_ + 192));            \
    const float* gp_ = gib + (size_t)(TLOAD) * S;                              \
    LD[0] = gp_[cg]; LD[1] = gp_[cg + 128]; LD[2] = gp_[cg + 256];             \
    f32x4 ac_[3];                                                              \
    _Pragma("unroll")                                                          \
    for (int g = 0; g < 3; g++) ac_[g] = (f32x4){0.f, 0.f, 0.f, 0.f};          \
    _Pragma("unroll")                                                          \
    for (int kc = 0; kc < 4; kc++) {                                           \
      _Pragma("unroll")                                                        \
      for (int g = 0; g < 3; g++)                                              \
        ac_[g] = __builtin_amdgcn_mfma_f32_16x16x32_f16(af_[kc], wf[g][kc],    \
                                                        ac_[g], 0, 0, 0);      \
    }                                                                          \
    const float q_  = CUR[2] * L2E2;                                           \
    const float yr_ = fmaf(CUR[0], L2E, ac_[0][0]);                            \
    const float r_  = rcp_(1.f + EXP2(-yr_));                                  \
    const float yz_ = fmaf(CUR[1], L2E, ac_[1][0]);                            \
    const float z_  = rcp_(1.f + EXP2(-yz_));                                  \
    const float yn_ = fmaf(r_, ac_[2][0] + bh, q_);                            \
    const float u_  = rcp_(1.f + EXP2(yn_));                                   \
    const float n_  = fmaf(-2.f, u_, 1.f);                                     \
    hj = n_ + z_ * (hj - n_);                                                  \
    hs += hj;                                                                  \
    if (kq == 0) h2_sh[(PB) ^ 1][cg] = (_Float16)hj;                           \
    __syncthreads();                                                           \
  }

__device__ __forceinline__ void rec_body(
    int b,
    const float* __restrict__ gi, const float* __restrict__ w_hh,
    const float* __restrict__ b_hh,
    const float* __restrict__ w_proj, const float* __restrict__ b_proj,
    float* __restrict__ out, float* __restrict__ state,
    int t0, int t1)
{
    const int tid  = threadIdx.x;
    const int w    = tid >> 6;     // wave 0..7
    const int lane = tid & 63;
    const int ln   = lane & 15;
    const int kq   = lane >> 4;
    const int wh   = w & 3;
    const int f    = w >> 2;
    const int cg   = 16 * wh + ln + 64 * f;
    const int nT   = t1 - t0;      // multiple of 4

    __shared__ _Float16 h2_sh[2][HID_];
    __shared__ float pooled[HID_];

    // B-frags pre-scaled: r,z by log2(e); n by 2*log2(e) (exp2-direct gates)
    f16x8 wf[3][4];
    #pragma unroll
    for (int g = 0; g < 3; g++) {
        const float s = (g == 2) ? L2E2 : L2E;
        const float* wr = w_hh + (size_t)(128 * g + cg) * HID_;
        #pragma unroll
        for (int kc = 0; kc < 4; kc++) {
            const float* p = wr + kc * 32 + kq * 8;
            float4 q0 = *reinterpret_cast<const float4*>(p);
            float4 q1 = *reinterpret_cast<const float4*>(p + 4);
            q0.x *= s; q0.y *= s; q0.z *= s; q0.w *= s;
            q1.x *= s; q1.y *= s; q1.z *= s; q1.w *= s;
            wf[g][kc] = pack8_(q0, q1);
        }
    }
    const float bh = L2E2 * b_hh[256 + cg];

    float hj, hs;
    if (t0 == 0) { hj = hs = 0.f; }
    else {
        hj = state[b * HID_ + cg];
        hs = state[B_ * HID_ + b * HID_ + cg];
    }
    if (kq == 0) h2_sh[0][cg] = (_Float16)hj;
    __syncthreads();

    const float* gib = gi + (size_t)b * G3_;
    const size_t S = (size_t)B_ * G3_;

    float g0[3], g1[3], g2[3], g3[3];
    {
        const float* p0 = gib;
        const float* p1 = gib + S;
        g0[0] = p0[cg]; g0[1] = p0[cg + 128]; g0[2] = p0[cg + 256];
        g1[0] = p1[cg]; g1[1] = p1[cg + 128]; g1[2] = p1[cg + 256];
    }

    int pb = 0;
    const int nTm1 = nT - 1;
    for (int t = 0; t < nT; t += 4) {
        int t2 = t + 2 < nTm1 ? t + 2 : nTm1;
        int t3 = t + 3 < nTm1 ? t + 3 : nTm1;
        int t4 = t + 4 < nTm1 ? t + 4 : nTm1;
        int t5 = t + 5 < nTm1 ? t + 5 : nTm1;
        REC_STEP(g0, g2, t2, pb); pb ^= 1;
        REC_STEP(g1, g3, t3, pb); pb ^= 1;
        REC_STEP(g2, g0, t4, pb); pb ^= 1;
        REC_STEP(g3, g1, t5, pb); pb ^= 1;
    }

    if (t1 < T_) {
        if (kq == 0) {
            state[b * HID_ + cg]             = hj;
            state[B_ * HID_ + b * HID_ + cg] = hs;
        }
    } else {
        if (kq == 0) pooled[cg] = hs * (1.f / (float)T_);
        __syncthreads();
        if (tid < E_) {
            const float4* wpj = reinterpret_cast<const float4*>(w_proj + (size_t)tid * HID_);
            const float4* pp  = reinterpret_cast<const float4*>(pooled);
            float a0 = 0.f, a1 = 0.f, a2 = 0.f, a3 = 0.f;
            #pragma unroll
            for (int k = 0; k < 32; k++) {
                float4 wv = wpj[k]; float4 pv = pp[k];
                a0 = fmaf(wv.x, pv.x, a0);
                a1 = fmaf(wv.y, pv.y, a1);
                a2 = fmaf(wv.z, pv.z, a2);
                a3 = fmaf(wv.w, pv.w, a3);
            }
            out[b * E_ + tid] = (a0 + a1) + (a2 + a3) + b_proj[tid];
        }
    }
}

// ---------------------------------------------------------------------------
// Fused pipeline dispatch (round-4-passing structure): blocks [0, nRec) run
// rec(chunk i-1), blocks [nRec, nRec+gemmBlocks) run gi_gemm(chunk i). No
// intra-dispatch data dependency: rec reads the gi buffer written by the
// PREVIOUS dispatch (stream order = happens-before). rec blocks first in the
// grid so they get CUs immediately; the 64 gemm blocks beyond 256 CUs queue
// and backfill as 22-us gemm blocks retire (all gemm done in ~50us << rec's
// ~167us chunk).
// ---------------------------------------------------------------------------
__global__ __launch_bounds__(512, 1)
void fused(const float* __restrict__ x, const float* __restrict__ w_ih,
           const float* __restrict__ b_ih, const float* __restrict__ w_hh,
           const float* __restrict__ b_hh,
           const float* __restrict__ w_proj, const float* __restrict__ b_proj,
           const float* __restrict__ gi_rec, float* __restrict__ gi_out,
           float* __restrict__ out, float* __restrict__ state,
           int trec0, int trec1, int tg0, int nRec, int nTiles)
{
    const int bid = (int)blockIdx.x;
    if (bid < nRec) {
        rec_body(bid, gi_rec, w_hh, b_hh, w_proj, b_proj, out, state, trec0, trec1);
    } else {
        gemm_body(bid - nRec, nTiles, tg0, x, w_ih, b_ih, b_hh, gi_out);
    }
}

extern "C" void kernel_launch(void* const* d_in, const int* in_sizes, int n_in,
                              void* d_out, int out_size, void* d_ws, size_t ws_size,
                              hipStream_t stream)
{
    const float* x      = (const float*)d_in[0];
    const float* w_ih   = (const float*)d_in[1];
    const float* w_hh   = (const float*)d_in[2];
    const float* b_ih   = (const float*)d_in[3];
    const float* b_hh   = (const float*)d_in[4];
    const float* w_proj = (const float*)d_in[5];
    const float* b_proj = (const float*)d_in[6];
    float* out = (float*)d_out;

    const size_t state_bytes = (size_t)2 * B_ * HID_ * sizeof(float);
    const size_t per_t = (size_t)B_ * G3_ * sizeof(float);

    if (ws_size >= 2 * (size_t)CT_ * per_t + state_bytes) {
        // Pipelined path: double-buffered CT_-sized gi chunks.
        float* buf[2] = { (float*)d_ws,
                          (float*)((char*)d_ws + (size_t)CT_ * per_t) };
        float* state  = (float*)((char*)d_ws + 2 * (size_t)CT_ * per_t);
        const int nTiles = CT_ / TS_;        // 4
        const int nC = T_ / CT_;             // 4
        for (int i = 0; i <= nC; i++) {
            const int rb = (i > 0)  ? B_ : 0;
            const int gb = (i < nC) ? nTiles * B_ : 0;
            fused<<<dim3(rb + gb), dim3(512), 0, stream>>>(
                x, w_ih, b_ih, w_hh, b_hh, w_proj, b_proj,
                buf[(i + 1) & 1] /* = buf[(i-1)&1] */, buf[i & 1],
                out, state,
                (i - 1) * CT_, i * CT_, i * CT_, rb, nTiles);
        }
    } else {
        // Serial fallback: single buffer, gemm dispatch then rec dispatch.
        size_t avail = ws_size > state_bytes ? ws_size - state_bytes : 0;
        int cT = (int)(avail / per_t);
        if (cT > T_) cT = T_;
        cT &= ~(TS_ - 1);
        if (cT < TS_) cT = TS_;
        float* buf0  = (float*)d_ws;
        float* state = (float*)((char*)d_ws + (size_t)cT * per_t);
        for (int t0 = 0; t0 < T_; t0 += cT) {
            int t1 = t0 + cT; if (t1 > T_) t1 = T_;
            int nt = t1 - t0;
            fused<<<dim3((nt / TS_) * B_), dim3(512), 0, stream>>>(
                x, w_ih, b_ih, w_hh, b_hh, w_proj, b_proj,
                buf0, buf0, out, state, 0, 0, t0, 0, nt / TS_);
            fused<<<dim3(B_), dim3(512), 0, stream>>>(
                x, w_ih, b_ih, w_hh, b_hh, w_proj, b_proj,
                buf0, buf0, out, state, t0, t1, 0, B_, nt / TS_);
        }
    }
}

// Round 9
// 833.555 us; speedup vs baseline: 1.5165x; 1.0032x over previous
//
#include <hip/hip_runtime.h>
#include <math.h>

#define B_   64
#define T_   2048
#define HID_ 128
#define G3_  384   // 3*HID
#define IN_  128
#define E_   64

#define TS_  128   // t-tile of gi GEMM block

typedef _Float16 f16x8 __attribute__((ext_vector_type(8)));
typedef float    f32x4 __attribute__((ext_vector_type(4)));

#define L2E  1.4426950408889634f   // log2(e)
#define L2E2 2.8853900817779268f   // 2*log2(e)

#if __has_builtin(__builtin_amdgcn_exp2f)
#define EXP2(x) __builtin_amdgcn_exp2f(x)
#else
#define EXP2(x) __expf((x) * 0.6931471805599453f)
#endif

__device__ __forceinline__ float rcp_(float x) { return __builtin_amdgcn_rcpf(x); }

// pack 8 f32 -> f16x8 via 4x cvt_pkrtz
__device__ __forceinline__ f16x8 pack8_(float4 a, float4 b) {
    uint4 u;
    u.x = __builtin_bit_cast(unsigned, __builtin_amdgcn_cvt_pkrtz(a.x, a.y));
    u.y = __builtin_bit_cast(unsigned, __builtin_amdgcn_cvt_pkrtz(a.z, a.w));
    u.z = __builtin_bit_cast(unsigned, __builtin_amdgcn_cvt_pkrtz(b.x, b.y));
    u.w = __builtin_bit_cast(unsigned, __builtin_amdgcn_cvt_pkrtz(b.z, b.w));
    return __builtin_bit_cast(f16x8, u);
}

// ---------------------------------------------------------------------------
// gi GEMM body (round-8-passing version, unchanged). 8 waves / 512 threads,
// two column passes of 12 n-tiles. Wave w owns one 16-row m-tile; MFMA
// layout session-verified (A row = ln, C/D row = kq*4+r, col = ln).
// gi rows are chunk-relative (tl_base); x rows absolute (t0 + tl_base).
// ---------------------------------------------------------------------------
__device__ __forceinline__ void gemm_body(
    int g, int nTiles, int t0,
    const float* __restrict__ x, const float* __restrict__ w_ih,
    const float* __restrict__ b_ih, const float* __restrict__ b_hh,
    float* __restrict__ gi)
{
    const int tid = threadIdx.x;
    const int w   = tid >> 6;      // 0..7
    const int l   = tid & 63;
    const int ln  = l & 15;
    const int kq  = l >> 4;
    const int tt  = g % nTiles;
    const int b   = g / nTiles;
    const int tl_base = tt * TS_ + w * 16;

    const float* xb = x + ((size_t)b * T_ + (size_t)(t0 + tl_base)) * IN_;

    f16x8 afr[4];
    #pragma unroll
    for (int kc = 0; kc < 4; kc++) {
        const float* xr = xb + (size_t)ln * IN_ + kc * 32 + kq * 8;
        float4 p0 = *reinterpret_cast<const float4*>(xr);
        float4 p1 = *reinterpret_cast<const float4*>(xr + 4);
        afr[kc] = pack8_(p0, p1);
    }

    #pragma unroll
    for (int half = 0; half < 2; half++) {
        f32x4 acc[12];
        #pragma unroll
        for (int j = 0; j < 12; j++) acc[j] = (f32x4){0.f, 0.f, 0.f, 0.f};

        #pragma unroll
        for (int kc = 0; kc < 4; kc++) {
            #pragma unroll
            for (int j = 0; j < 12; j++) {
                const int nt = half * 12 + j;
                const float* wr = w_ih + (size_t)(nt * 16 + ln) * IN_ + kc * 32 + kq * 8;
                float4 q0 = *reinterpret_cast<const float4*>(wr);
                float4 q1 = *reinterpret_cast<const float4*>(wr + 4);
                const f16x8 bfr = pack8_(q0, q1);
                acc[j] = __builtin_amdgcn_mfma_f32_16x16x32_f16(afr[kc], bfr, acc[j], 0, 0, 0);
            }
        }

        #pragma unroll
        for (int j = 0; j < 12; j++) {
            const int col = half * 192 + j * 16 + ln;
            const float bias = b_ih[col] + (col < 256 ? b_hh[col] : 0.f);
            #pragma unroll
            for (int r = 0; r < 4; r++) {
                const size_t trow = (size_t)(tl_base + kq * 4 + r);   // chunk-relative
                gi[trow * (B_ * G3_) + (size_t)b * G3_ + col] = acc[j][r] + bias;
            }
        }
    }
}

// ---------------------------------------------------------------------------
// GRU recurrence step. Arithmetic is BIT-IDENTICAL to round 8 (each gate's
// accumulator sums kc0->kc3 in order; gate formulas unchanged); only the
// ISSUE ORDER changed: g0's 4 MFMAs, then g2's, then r's exp2/rcp chain
// (overlaps g1's MFMA issue), then n, then z. Hides ~50-70 cyc of the
// serial gate chain under MFMA issue instead of after it.
// ---------------------------------------------------------------------------
#define REC_STEP(CUR, LD, TLOAD, PB)                                           \
  {                                                                            \
    const char* hb_ = (const char*)(&h2_sh[PB][0]) + kq * 16;                  \
    f16x8 af_[4];                                                              \
    af_[0] = __builtin_bit_cast(f16x8, *(const uint4*)(hb_));                  \
    af_[1] = __builtin_bit_cast(f16x8, *(const uint4*)(hb_ + 64));             \
    af_[2] = __builtin_bit_cast(f16x8, *(const uint4*)(hb_ + 128));            \
    af_[3] = __builtin_bit_cast(f16x8, *(const uint4*)(hb_ + 192));            \
    const float* gp_ = gib + (size_t)(TLOAD) * S;                              \
    LD[0] = gp_[cg]; LD[1] = gp_[cg + 128]; LD[2] = gp_[cg + 256];             \
    f32x4 a0_ = (f32x4){0.f, 0.f, 0.f, 0.f};                                   \
    f32x4 a1_ = (f32x4){0.f, 0.f, 0.f, 0.f};                                   \
    f32x4 a2_ = (f32x4){0.f, 0.f, 0.f, 0.f};                                   \
    a0_ = __builtin_amdgcn_mfma_f32_16x16x32_f16(af_[0], wf[0][0], a0_, 0, 0, 0); \
    a0_ = __builtin_amdgcn_mfma_f32_16x16x32_f16(af_[1], wf[0][1], a0_, 0, 0, 0); \
    a0_ = __builtin_amdgcn_mfma_f32_16x16x32_f16(af_[2], wf[0][2], a0_, 0, 0, 0); \
    a0_ = __builtin_amdgcn_mfma_f32_16x16x32_f16(af_[3], wf[0][3], a0_, 0, 0, 0); \
    a2_ = __builtin_amdgcn_mfma_f32_16x16x32_f16(af_[0], wf[2][0], a2_, 0, 0, 0); \
    a2_ = __builtin_amdgcn_mfma_f32_16x16x32_f16(af_[1], wf[2][1], a2_, 0, 0, 0); \
    a2_ = __builtin_amdgcn_mfma_f32_16x16x32_f16(af_[2], wf[2][2], a2_, 0, 0, 0); \
    a2_ = __builtin_amdgcn_mfma_f32_16x16x32_f16(af_[3], wf[2][3], a2_, 0, 0, 0); \
    const float yr_ = fmaf(CUR[0], L2E, a0_[0]);                               \
    const float r_  = rcp_(1.f + EXP2(-yr_));                                  \
    a1_ = __builtin_amdgcn_mfma_f32_16x16x32_f16(af_[0], wf[1][0], a1_, 0, 0, 0); \
    a1_ = __builtin_amdgcn_mfma_f32_16x16x32_f16(af_[1], wf[1][1], a1_, 0, 0, 0); \
    a1_ = __builtin_amdgcn_mfma_f32_16x16x32_f16(af_[2], wf[1][2], a1_, 0, 0, 0); \
    a1_ = __builtin_amdgcn_mfma_f32_16x16x32_f16(af_[3], wf[1][3], a1_, 0, 0, 0); \
    const float q_  = CUR[2] * L2E2;                                           \
    const float yn_ = fmaf(r_, a2_[0] + bh, q_);                               \
    const float u_  = rcp_(1.f + EXP2(yn_));                                   \
    const float n_  = fmaf(-2.f, u_, 1.f);                                     \
    const float yz_ = fmaf(CUR[1], L2E, a1_[0]);                               \
    const float z_  = rcp_(1.f + EXP2(-yz_));                                  \
    hj = n_ + z_ * (hj - n_);                                                  \
    hs += hj;                                                                  \
    if (kq == 0) h2_sh[(PB) ^ 1][cg] = (_Float16)hj;                           \
    __syncthreads();                                                           \
  }

__device__ __forceinline__ void rec_body(
    int b,
    const float* __restrict__ gi, const float* __restrict__ w_hh,
    const float* __restrict__ b_hh,
    const float* __restrict__ w_proj, const float* __restrict__ b_proj,
    float* __restrict__ out, float* __restrict__ state,
    int t0, int t1)
{
    const int tid  = threadIdx.x;
    const int w    = tid >> 6;     // wave 0..7
    const int lane = tid & 63;
    const int ln   = lane & 15;
    const int kq   = lane >> 4;
    const int wh   = w & 3;
    const int f    = w >> 2;
    const int cg   = 16 * wh + ln + 64 * f;
    const int nT   = t1 - t0;      // multiple of 4

    __shared__ _Float16 h2_sh[2][HID_];
    __shared__ float pooled[HID_];

    // B-frags pre-scaled: r,z by log2(e); n by 2*log2(e) (exp2-direct gates)
    f16x8 wf[3][4];
    #pragma unroll
    for (int g = 0; g < 3; g++) {
        const float s = (g == 2) ? L2E2 : L2E;
        const float* wr = w_hh + (size_t)(128 * g + cg) * HID_;
        #pragma unroll
        for (int kc = 0; kc < 4; kc++) {
            const float* p = wr + kc * 32 + kq * 8;
            float4 q0 = *reinterpret_cast<const float4*>(p);
            float4 q1 = *reinterpret_cast<const float4*>(p + 4);
            q0.x *= s; q0.y *= s; q0.z *= s; q0.w *= s;
            q1.x *= s; q1.y *= s; q1.z *= s; q1.w *= s;
            wf[g][kc] = pack8_(q0, q1);
        }
    }
    const float bh = L2E2 * b_hh[256 + cg];

    float hj, hs;
    if (t0 == 0) { hj = hs = 0.f; }
    else {
        hj = state[b * HID_ + cg];
        hs = state[B_ * HID_ + b * HID_ + cg];
    }
    if (kq == 0) h2_sh[0][cg] = (_Float16)hj;
    __syncthreads();

    const float* gib = gi + (size_t)b * G3_;
    const size_t S = (size_t)B_ * G3_;

    float g0[3], g1[3], g2[3], g3[3];
    {
        const float* p0 = gib;
        const float* p1 = gib + S;
        g0[0] = p0[cg]; g0[1] = p0[cg + 128]; g0[2] = p0[cg + 256];
        g1[0] = p1[cg]; g1[1] = p1[cg + 128]; g1[2] = p1[cg + 256];
    }

    int pb = 0;
    const int nTm1 = nT - 1;
    for (int t = 0; t < nT; t += 4) {
        int t2 = t + 2 < nTm1 ? t + 2 : nTm1;
        int t3 = t + 3 < nTm1 ? t + 3 : nTm1;
        int t4 = t + 4 < nTm1 ? t + 4 : nTm1;
        int t5 = t + 5 < nTm1 ? t + 5 : nTm1;
        REC_STEP(g0, g2, t2, pb); pb ^= 1;
        REC_STEP(g1, g3, t3, pb); pb ^= 1;
        REC_STEP(g2, g0, t4, pb); pb ^= 1;
        REC_STEP(g3, g1, t5, pb); pb ^= 1;
    }

    if (t1 < T_) {
        if (kq == 0) {
            state[b * HID_ + cg]             = hj;
            state[B_ * HID_ + b * HID_ + cg] = hs;
        }
    } else {
        if (kq == 0) pooled[cg] = hs * (1.f / (float)T_);
        __syncthreads();
        if (tid < E_) {
            const float4* wpj = reinterpret_cast<const float4*>(w_proj + (size_t)tid * HID_);
            const float4* pp  = reinterpret_cast<const float4*>(pooled);
            float a0 = 0.f, a1 = 0.f, a2 = 0.f, a3 = 0.f;
            #pragma unroll
            for (int k = 0; k < 32; k++) {
                float4 wv = wpj[k]; float4 pv = pp[k];
                a0 = fmaf(wv.x, pv.x, a0);
                a1 = fmaf(wv.y, pv.y, a1);
                a2 = fmaf(wv.z, pv.z, a2);
                a3 = fmaf(wv.w, pv.w, a3);
            }
            out[b * E_ + tid] = (a0 + a1) + (a2 + a3) + b_proj[tid];
        }
    }
}

// ---------------------------------------------------------------------------
// Fused pipeline dispatch (round-8-passing structure, unchanged): blocks
// [0, nRec) run rec(chunk i-1), blocks [nRec, ...) run gi_gemm(chunk i).
// rec reads the gi buffer written by the PREVIOUS dispatch (stream order =
// happens-before). rec blocks first in the grid.
// ---------------------------------------------------------------------------
__global__ __launch_bounds__(512, 1)
void fused(const float* __restrict__ x, const float* __restrict__ w_ih,
           const float* __restrict__ b_ih, const float* __restrict__ w_hh,
           const float* __restrict__ b_hh,
           const float* __restrict__ w_proj, const float* __restrict__ b_proj,
           const float* __restrict__ gi_rec, float* __restrict__ gi_out,
           float* __restrict__ out, float* __restrict__ state,
           int trec0, int trec1, int tg0, int nRec, int nTiles)
{
    const int bid = (int)blockIdx.x;
    if (bid < nRec) {
        rec_body(bid, gi_rec, w_hh, b_hh, w_proj, b_proj, out, state, trec0, trec1);
    } else {
        gemm_body(bid - nRec, nTiles, tg0, x, w_ih, b_ih, b_hh, gi_out);
    }
}

extern "C" void kernel_launch(void* const* d_in, const int* in_sizes, int n_in,
                              void* d_out, int out_size, void* d_ws, size_t ws_size,
                              hipStream_t stream)
{
    const float* x      = (const float*)d_in[0];
    const float* w_ih   = (const float*)d_in[1];
    const float* w_hh   = (const float*)d_in[2];
    const float* b_ih   = (const float*)d_in[3];
    const float* b_hh   = (const float*)d_in[4];
    const float* w_proj = (const float*)d_in[5];
    const float* b_proj = (const float*)d_in[6];
    float* out = (float*)d_out;

    const size_t state_bytes = (size_t)2 * B_ * HID_ * sizeof(float);
    const size_t per_t = (size_t)B_ * G3_ * sizeof(float);

    // Geometric chunk schedule: smallest first minimizes the exposed gemm
    // prologue; each gemm(c[i]) fits under rec(c[i-1]) with >=1.3x margin
    // (gemm ~8.5 steps/us on free CUs vs rec ~3.1 steps/us).
    const int NCK = 4;
    const int ck[NCK] = {128, 256, 640, 1024};
    // buf0 holds chunks 0,2 (max 640 rows); buf1 holds chunks 1,3 (max 1024).
    const size_t buf0_rows = 640, buf1_rows = 1024;
    const size_t need = (buf0_rows + buf1_rows) * per_t + state_bytes;

    if (ws_size >= need) {
        float* buf[2] = { (float*)d_ws,
                          (float*)((char*)d_ws + buf0_rows * per_t) };
        float* state  = (float*)((char*)d_ws + (buf0_rows + buf1_rows) * per_t);
        int st[NCK + 1];
        st[0] = 0;
        for (int i = 0; i < NCK; i++) st[i + 1] = st[i] + ck[i];
        for (int i = 0; i <= NCK; i++) {
            const int rb = (i > 0)   ? B_ : 0;
            const int gb = (i < NCK) ? (ck[i] / TS_) * B_ : 0;
            const int trec0 = (i > 0) ? st[i - 1] : 0;
            const int trec1 = (i > 0) ? st[i]     : 0;
            const int tg0   = (i < NCK) ? st[i] : 0;
            const int nT    = (i < NCK) ? ck[i] / TS_ : 1;
            fused<<<dim3(rb + gb), dim3(512), 0, stream>>>(
                x, w_ih, b_ih, w_hh, b_hh, w_proj, b_proj,
                buf[(i + 1) & 1] /* = buf[(i-1)&1] */, buf[i & 1],
                out, state, trec0, trec1, tg0, rb, nT);
        }
    } else {
        // Serial fallback: single buffer, gemm dispatch then rec dispatch.
        size_t avail = ws_size > state_bytes ? ws_size - state_bytes : 0;
        int cT = (int)(avail / per_t);
        if (cT > T_) cT = T_;
        cT &= ~(TS_ - 1);
        if (cT < TS_) cT = TS_;
        float* buf0  = (float*)d_ws;
        float* state = (float*)((char*)d_ws + (size_t)cT * per_t);
        for (int t0 = 0; t0 < T_; t0 += cT) {
            int t1 = t0 + cT; if (t1 > T_) t1 = T_;
            int nt = t1 - t0;
            fused<<<dim3((nt / TS_) * B_), dim3(512), 0, stream>>>(
                x, w_ih, b_ih, w_hh, b_hh, w_proj, b_proj,
                buf0, buf0, out, state, 0, 0, t0, 0, nt / TS_);
            fused<<<dim3(B_), dim3(512), 0, stream>>>(
                x, w_ih, b_ih, w_hh, b_hh, w_proj, b_proj,
                buf0, buf0, out, state, t0, t1, 0, B_, nt / TS_);
        }
    }
}